// Round 10
// baseline (44.717 us; speedup 1.0000x reference)
//
#include <hip/hip_runtime.h>

#define NATOMS 8192
#define NFREE  4096

constexpr int TPB = 256;            // threads per block (4 waves)
constexpr int IPT = 4;              // i-atoms per thread (2 packed f32x2 groups)
constexpr int TI  = TPB * IPT;      // 1024 i-atoms per block
constexpr int JT  = 32;             // j-atoms staged in LDS per block
constexpr int GI  = NATOMS / TI;    // 8 i-slabs
constexpr int GJ  = NATOMS / JT;    // 256 j-tiles
constexpr int TPS = TI / JT;        // 32 j-tiles spanning one i-slab
// Triangle grid: slab x dispatches j-tiles y in [TPS*x, GJ).
__device__ __constant__ const int S_START[GI + 1] = {0, 256, 480, 672, 832, 960, 1056, 1120, 1152};
constexpr int NVBLK = 1152;         // 4.5 blocks/CU -> all resident
constexpr int NSLOT = 8;            // V accumulation slots (avoid same-address atomic burst)

typedef __attribute__((ext_vector_type(2))) float f32x2;

// d = a * broadcast(b.lo) + c   (VOP3P op_sel: both result halves read src1's low reg)
__device__ __forceinline__ f32x2 pk_fma_blo(f32x2 a, f32x2 b, f32x2 c) {
    f32x2 d;
    asm("v_pk_fma_f32 %0, %1, %2, %3 op_sel:[0,0,0] op_sel_hi:[1,0,1]"
        : "=v"(d) : "v"(a), "v"(b), "v"(c));
    return d;
}
// d = a * broadcast(b.hi) + c
__device__ __forceinline__ f32x2 pk_fma_bhi(f32x2 a, f32x2 b, f32x2 c) {
    f32x2 d;
    asm("v_pk_fma_f32 %0, %1, %2, %3 op_sel:[0,1,0] op_sel_hi:[1,1,1]"
        : "=v"(d) : "v"(a), "v"(b), "v"(c));
    return d;
}
// d = a + broadcast(b.hi)
__device__ __forceinline__ f32x2 pk_add_bhi(f32x2 a, f32x2 b) {
    f32x2 d;
    asm("v_pk_add_f32 %0, %1, %2 op_sel:[0,1] op_sel_hi:[1,1]"
        : "=v"(d) : "v"(a), "v"(b));
    return d;
}

__device__ __forceinline__ float wave_reduce(float v) {
#pragma unroll
    for (int off = 32; off > 0; off >>= 1)
        v += __shfl_down(v, off, 64);
    return v;
}

// Triangle all-pairs sum of 1/r over i<j, coords direct from q/x0
// (free_idx = arange(NFREE): atoms [0,NFREE) from q, rest from x0; slab/tile
// boundaries never straddle NFREE). r2 = si + sj - 2 xi.xj, (-2xi) prescaled.
// Fused finish: per-block atomicAdd into 8 V-slots (memory-side coherent, no
// cache fence needed), vmcnt-drain, counter bump; last block computes T and out.
__global__ __launch_bounds__(TPB, 5) void pair_kernel(const float* __restrict__ q,
                                                      const float* __restrict__ x0,
                                                      const float4* __restrict__ qd4,
                                                      float* __restrict__ vslot,
                                                      int* __restrict__ counter,
                                                      float* __restrict__ out) {
    __shared__ float4 sj[JT];
    const int bid = blockIdx.x;

    int x = 0;
#pragma unroll
    for (int e = 1; e < GI; ++e) x += (bid >= S_START[e]);
    const int y  = bid - S_START[x] + TPS * x;
    const int i0 = x * TI;
    const int j0 = y * JT;
    const int t  = threadIdx.x;

    // Stage j-tile into LDS as (x, y, z, |x|^2).
    if (t < JT) {
        const int ja = j0 + t;
        const float* p = (ja < NFREE) ? (q + 3 * ja) : (x0 + 3 * ja);
        float xx = p[0], yy = p[1], zz = p[2];
        sj[t] = make_float4(xx, yy, zz, fmaf(xx, xx, fmaf(yy, yy, zz * zz)));
    }

    // i-side: prescaled (-2x) and |x|^2, packed as 2 atoms per f32x2.
    const float* isrc = (i0 < NFREE) ? q : x0;
    f32x2 ax2[IPT / 2], ay2[IPT / 2], az2[IPT / 2], s2[IPT / 2];
    float acc[IPT];
    int m[IPT];
    const int rel0 = j0 - i0;
#pragma unroll
    for (int k = 0; k < IPT; ++k) {
        const int ia = i0 + t + k * TPB;
        float xx = isrc[3 * ia + 0], yy = isrc[3 * ia + 1], zz = isrc[3 * ia + 2];
        ax2[k / 2][k & 1] = -2.f * xx;
        ay2[k / 2][k & 1] = -2.f * yy;
        az2[k / 2][k & 1] = -2.f * zz;
        s2[k / 2][k & 1]  = fmaf(xx, xx, fmaf(yy, yy, zz * zz));
        acc[k] = 0.f;
        m[k] = t + k * TPB - rel0;   // keep iff m[k] < j_local (diag band only)
    }
    __syncthreads();

    if (rel0 < TI) {
        // Diagonal-band tile: keep only i<j (select also drops the i==j inf/NaN).
#pragma unroll
        for (int j = 0; j < JT; ++j) {
            const float4 pj = sj[j];
            f32x2 pxy; pxy.x = pj.x; pxy.y = pj.y;
            f32x2 pzw; pzw.x = pj.z; pzw.y = pj.w;
#pragma unroll
            for (int g = 0; g < IPT / 2; ++g) {
                f32x2 d = pk_fma_blo(ax2[g], pxy, s2[g]);
                d = pk_fma_bhi(ay2[g], pxy, d);
                d = pk_fma_blo(az2[g], pzw, d);
                d = pk_add_bhi(d, pzw);
                float r0 = __builtin_amdgcn_rsqf(d.x);
                float r1 = __builtin_amdgcn_rsqf(d.y);
                acc[2 * g + 0] += (m[2 * g + 0] < j) ? r0 : 0.f;
                acc[2 * g + 1] += (m[2 * g + 1] < j) ? r1 : 0.f;
            }
        }
    } else {
#pragma unroll
        for (int j = 0; j < JT; ++j) {
            const float4 pj = sj[j];
            f32x2 pxy; pxy.x = pj.x; pxy.y = pj.y;
            f32x2 pzw; pzw.x = pj.z; pzw.y = pj.w;
#pragma unroll
            for (int g = 0; g < IPT / 2; ++g) {
                f32x2 d = pk_fma_blo(ax2[g], pxy, s2[g]);
                d = pk_fma_bhi(ay2[g], pxy, d);
                d = pk_fma_blo(az2[g], pzw, d);
                d = pk_add_bhi(d, pzw);
                acc[2 * g + 0] += __builtin_amdgcn_rsqf(d.x);
                acc[2 * g + 1] += __builtin_amdgcn_rsqf(d.y);
            }
        }
    }

    float v = (acc[0] + acc[1]) + (acc[2] + acc[3]);
    v = wave_reduce(v);
    __shared__ float s[TPB / 64];
    __shared__ bool sdone;
    int lane = t & 63, wid = t >> 6;
    if (lane == 0) s[wid] = v;
    __syncthreads();
    if (t == 0) {
        float vtot = (s[0] + s[1]) + (s[2] + s[3]);
        atomicAdd(&vslot[bid & (NSLOT - 1)], vtot);       // memory-side, device-scope
        asm volatile("s_waitcnt vmcnt(0)" ::: "memory");  // order V-add before counter
        int old = atomicAdd(counter, 1);
        sdone = (old == NVBLK - 1);
    }
    __syncthreads();

    if (sdone) {
        // Last block: every prior block's V-add completed before its counter bump.
        float tq = 0.f;
        for (int i = t; i < (NFREE * 3) / 4; i += TPB) {
            float4 u = qd4[i];
            tq += fmaf(u.x, u.x, fmaf(u.y, u.y, fmaf(u.z, u.z, u.w * u.w)));
        }
        tq = wave_reduce(tq);
        if (lane == 0) s[wid] = tq;
        __syncthreads();
        if (t == 0) {
            float T = (s[0] + s[1]) + (s[2] + s[3]);
            float V = 0.f;
#pragma unroll
            for (int i = 0; i < NSLOT; ++i)
                V += __hip_atomic_load(&vslot[i], __ATOMIC_RELAXED, __HIP_MEMORY_SCOPE_AGENT);
            out[0] = 0.5f * T - 2.0f * V;   // V2 = 2 * sum_{i<j} 1/r
        }
    }
}

extern "C" void kernel_launch(void* const* d_in, const int* in_sizes, int n_in,
                              void* d_out, int out_size, void* d_ws, size_t ws_size,
                              hipStream_t stream) {
    const float* q  = (const float*)d_in[0];
    const float* qd = (const float*)d_in[1];
    const float* x0 = (const float*)d_in[2];
    float* out = (float*)d_out;

    float* vslot   = (float*)d_ws;        // [NSLOT]
    int*   counter = (int*)d_ws + NSLOT;

    // Zero V-slots + counter each call (d_ws is not re-poisoned between replays).
    hipMemsetAsync(d_ws, 0, (NSLOT + 1) * sizeof(float), stream);
    pair_kernel<<<NVBLK, TPB, 0, stream>>>(q, x0, (const float4*)qd, vslot, counter, out);
}

// Round 11
// 18.544 us; speedup vs baseline: 2.4114x; 2.4114x over previous
//
#include <hip/hip_runtime.h>

#define NATOMS 8192
#define NFREE  4096

constexpr int TPB = 256;            // threads per block (4 waves)
constexpr int IPT = 8;              // i-atoms per thread (4 packed f32x2 groups)
constexpr int TI  = TPB * IPT;      // 2048 i-atoms per block
constexpr int JT  = 32;             // j-atoms staged in LDS per block
constexpr int GI  = NATOMS / TI;    // 4 i-slabs
constexpr int GJ  = NATOMS / JT;    // 256 j-tiles
constexpr int TPS = TI / JT;        // 64 j-tiles spanning one i-slab
// Triangle grid: slab x dispatches j-tiles y in [TPS*x, GJ).
__device__ __constant__ const int S_START[GI + 1] = {0, 256, 448, 576, 640};
constexpr int NVBLK = 640;          // 2.5 blocks/CU

typedef __attribute__((ext_vector_type(2))) float f32x2;

// d = a * broadcast(b.lo) + c   (VOP3P op_sel: both result halves read src1's low reg)
__device__ __forceinline__ f32x2 pk_fma_blo(f32x2 a, f32x2 b, f32x2 c) {
    f32x2 d;
    asm("v_pk_fma_f32 %0, %1, %2, %3 op_sel:[0,0,0] op_sel_hi:[1,0,1]"
        : "=v"(d) : "v"(a), "v"(b), "v"(c));
    return d;
}
// d = a * broadcast(b.hi) + c
__device__ __forceinline__ f32x2 pk_fma_bhi(f32x2 a, f32x2 b, f32x2 c) {
    f32x2 d;
    asm("v_pk_fma_f32 %0, %1, %2, %3 op_sel:[0,1,0] op_sel_hi:[1,1,1]"
        : "=v"(d) : "v"(a), "v"(b), "v"(c));
    return d;
}
// d = a + broadcast(b.hi)
__device__ __forceinline__ f32x2 pk_add_bhi(f32x2 a, f32x2 b) {
    f32x2 d;
    asm("v_pk_add_f32 %0, %1, %2 op_sel:[0,1] op_sel_hi:[1,1]"
        : "=v"(d) : "v"(a), "v"(b));
    return d;
}

__device__ __forceinline__ float wave_reduce(float v) {
#pragma unroll
    for (int off = 32; off > 0; off >>= 1)
        v += __shfl_down(v, off, 64);
    return v;
}

// Triangle all-pairs sum of 1/r over i<j, coords direct from q/x0
// (free_idx = arange(NFREE): atoms [0,NFREE) from q, rest from x0; slab/tile
// boundaries never straddle NFREE). r2 = si + sj - 2 xi.xj, (-2xi) prescaled.
// No cross-block sync, no atomics: per-block partial -> vpart (distinct slots).
__global__ __launch_bounds__(TPB) void pair_kernel(const float* __restrict__ q,
                                                   const float* __restrict__ x0,
                                                   float* __restrict__ vpart) {
    __shared__ float4 sj[JT];
    const int bid = blockIdx.x;

    int x = 0;
#pragma unroll
    for (int e = 1; e < GI; ++e) x += (bid >= S_START[e]);
    const int y  = bid - S_START[x] + TPS * x;
    const int i0 = x * TI;
    const int j0 = y * JT;
    const int t  = threadIdx.x;

    // Stage j-tile into LDS as (x, y, z, |x|^2).
    if (t < JT) {
        const int ja = j0 + t;
        const float* p = (ja < NFREE) ? (q + 3 * ja) : (x0 + 3 * ja);
        float xx = p[0], yy = p[1], zz = p[2];
        sj[t] = make_float4(xx, yy, zz, fmaf(xx, xx, fmaf(yy, yy, zz * zz)));
    }

    // i-side: prescaled (-2x) and |x|^2, packed as 2 atoms per f32x2.
    const float* isrc = (i0 < NFREE) ? q : x0;
    f32x2 ax2[IPT / 2], ay2[IPT / 2], az2[IPT / 2], s2[IPT / 2];
    float acc[IPT];
    int m[IPT];
    const int rel0 = j0 - i0;
#pragma unroll
    for (int k = 0; k < IPT; ++k) {
        const int ia = i0 + t + k * TPB;
        float xx = isrc[3 * ia + 0], yy = isrc[3 * ia + 1], zz = isrc[3 * ia + 2];
        ax2[k / 2][k & 1] = -2.f * xx;
        ay2[k / 2][k & 1] = -2.f * yy;
        az2[k / 2][k & 1] = -2.f * zz;
        s2[k / 2][k & 1]  = fmaf(xx, xx, fmaf(yy, yy, zz * zz));
        acc[k] = 0.f;
        m[k] = t + k * TPB - rel0;   // keep iff m[k] < j_local (diag band only)
    }
    __syncthreads();

    if (rel0 < TI) {
        // Diagonal-band tile: keep only i<j (select also drops the i==j inf/NaN).
#pragma unroll 8
        for (int j = 0; j < JT; ++j) {
            const float4 pj = sj[j];
            f32x2 pxy; pxy.x = pj.x; pxy.y = pj.y;
            f32x2 pzw; pzw.x = pj.z; pzw.y = pj.w;
#pragma unroll
            for (int g = 0; g < IPT / 2; ++g) {
                f32x2 d = pk_fma_blo(ax2[g], pxy, s2[g]);
                d = pk_fma_bhi(ay2[g], pxy, d);
                d = pk_fma_blo(az2[g], pzw, d);
                d = pk_add_bhi(d, pzw);
                float r0 = __builtin_amdgcn_rsqf(d.x);
                float r1 = __builtin_amdgcn_rsqf(d.y);
                acc[2 * g + 0] += (m[2 * g + 0] < j) ? r0 : 0.f;
                acc[2 * g + 1] += (m[2 * g + 1] < j) ? r1 : 0.f;
            }
        }
    } else {
#pragma unroll 8
        for (int j = 0; j < JT; ++j) {
            const float4 pj = sj[j];
            f32x2 pxy; pxy.x = pj.x; pxy.y = pj.y;
            f32x2 pzw; pzw.x = pj.z; pzw.y = pj.w;
#pragma unroll
            for (int g = 0; g < IPT / 2; ++g) {
                f32x2 d = pk_fma_blo(ax2[g], pxy, s2[g]);
                d = pk_fma_bhi(ay2[g], pxy, d);
                d = pk_fma_blo(az2[g], pzw, d);
                d = pk_add_bhi(d, pzw);
                acc[2 * g + 0] += __builtin_amdgcn_rsqf(d.x);
                acc[2 * g + 1] += __builtin_amdgcn_rsqf(d.y);
            }
        }
    }

    float v = ((acc[0] + acc[1]) + (acc[2] + acc[3])) +
              ((acc[4] + acc[5]) + (acc[6] + acc[7]));
    v = wave_reduce(v);
    __shared__ float s[TPB / 64];
    int lane = t & 63, wid = t >> 6;
    if (lane == 0) s[wid] = v;
    __syncthreads();
    if (t == 0)
        vpart[bid] = (s[0] + s[1]) + (s[2] + s[3]);
}

// out = 0.5*sum(qd^2) - 2*sum(vpart); single block, deterministic order.
__global__ void finalize(const float* __restrict__ vpart,
                         const float4* __restrict__ qd4,   // qd as 3072 float4
                         float* __restrict__ out) {
    float v = 0.f;
    for (int i = threadIdx.x; i < NVBLK; i += TPB) v += vpart[i];
    float tq = 0.f;
    for (int i = threadIdx.x; i < (NFREE * 3) / 4; i += TPB) {
        float4 u = qd4[i];
        tq += fmaf(u.x, u.x, fmaf(u.y, u.y, fmaf(u.z, u.z, u.w * u.w)));
    }
    v = wave_reduce(v);
    tq = wave_reduce(tq);
    __shared__ float sv[TPB / 64], st[TPB / 64];
    int lane = threadIdx.x & 63, wid = threadIdx.x >> 6;
    if (lane == 0) { sv[wid] = v; st[wid] = tq; }
    __syncthreads();
    if (threadIdx.x == 0) {
        float V = (sv[0] + sv[1]) + (sv[2] + sv[3]);
        float T = (st[0] + st[1]) + (st[2] + st[3]);
        out[0] = 0.5f * T - 2.0f * V;   // V2 = 2 * sum_{i<j} 1/r
    }
}

extern "C" void kernel_launch(void* const* d_in, const int* in_sizes, int n_in,
                              void* d_out, int out_size, void* d_ws, size_t ws_size,
                              hipStream_t stream) {
    const float* q  = (const float*)d_in[0];
    const float* qd = (const float*)d_in[1];
    const float* x0 = (const float*)d_in[2];
    float* out = (float*)d_out;

    float* vpart = (float*)d_ws;

    pair_kernel<<<NVBLK, TPB, 0, stream>>>(q, x0, vpart);
    finalize<<<1, TPB, 0, stream>>>(vpart, (const float4*)qd, out);
}